// Round 5
// baseline (192.291 us; speedup 1.0000x reference)
//
#include <hip/hip_runtime.h>
#include <math.h>

// Problem constants
#define NSEQ 4096      // N
#define MFT  4096      // complex FFT length (even/odd pack of 2N=8192 real)
#define CHX  2048      // B*H*D channels of x
#define CHA  512       // H*D channels of a

// float2-LDS padding: i + (i>>5); max padded index 4095+127=4222 -> 4224 f2.
// Keeps every exchange read/write phase <=2-way bank aliasing (free, m136),
// and exchange-2's 16 consecutive reads stay contiguous after padding.
#define LP2 4224
static __device__ __forceinline__ int pf(int i) { return i + (i >> 5); }

// ---------------------------------------------------------------- wave reduce
static __device__ __forceinline__ float wsum64(float v) {
    v += __shfl_xor(v, 1);
    v += __shfl_xor(v, 2);
    v += __shfl_xor(v, 4);
    v += __shfl_xor(v, 8);
    v += __shfl_xor(v, 16);
    v += __shfl_xor(v, 32);
    return v;
}

static __device__ __forceinline__ void ln1(float& x, float w, float b) {
    float mu = wsum64(x) * (1.0f / 64.0f);
    float d = x - mu;
    float v = wsum64(d * d) * (1.0f / 64.0f);
    x = d * rsqrtf(v + 1e-5f) * w + b;
}

// ---------------------------------------------------------------- k_pre
// blocks [0,2048): transpose x [32 slabs][4096 n][64 d] -> xT [32][64][4096]
// blocks [2048,2304): RPE MLP, 4 positions/wave, writes aT[c][m] directly
//   aT[c][m] = silu(gamma^m * rpe(m)[c]),  c = h*64+d.
// (The reference's trailing zero-row a[4096] only multiplies zero-padded x
//  for all kept outputs n<4096 -> dropped.)
__global__ __launch_bounds__(256) void k_pre(
    const float* __restrict__ x,
    const float* __restrict__ pp_w, const float* __restrict__ pp_b,
    const float* __restrict__ ln_w, const float* __restrict__ ln_b,
    const float* __restrict__ lw,   const float* __restrict__ lb,
    const float* __restrict__ oln_w,const float* __restrict__ oln_b,
    const float* __restrict__ out_w,const float* __restrict__ out_b,
    float* __restrict__ xT, float* __restrict__ aT)
{
    __shared__ float tile[64][65];
    const int t = threadIdx.x;

    if (blockIdx.x < 2048) {                 // ---- x transpose (R=4096, C=64)
        const int slab = blockIdx.x >> 6;    // 0..31
        const int r0 = (blockIdx.x & 63) * 64;
        const size_t base = (size_t)slab * 262144u;
        const int tc = t & 63, t4 = t >> 6;
        const float* s = x + base + (size_t)r0 * 64;
#pragma unroll
        for (int k = 0; k < 16; ++k) {
            int rr = t4 + k * 4;
            tile[rr][tc] = s[rr * 64 + tc];
        }
        __syncthreads();
        float* d = xT + base + r0;
#pragma unroll
        for (int k = 0; k < 16; ++k) {
            int cc = t4 + k * 4;
            d[(size_t)cc * 4096 + tc] = tile[tc][cc];
        }
        return;
    }

    // ---------------- RPE path
    const int wave = t >> 6;
    const int lane = t & 63;
    const int mbase = ((int)(blockIdx.x - 2048) * 4 + wave) * 4;  // 0..4092

    float mm[4], xx[4];
#pragma unroll
    for (int p = 0; p < 4; ++p) {
        mm[p] = (float)(mbase + p);
        xx[p] = fmaf(mm[p], pp_w[lane], pp_b[lane]);
    }

    for (int L = 0; L < 3; ++L) {
        float w = ln_w[L * 64 + lane], b = ln_b[L * 64 + lane];
        float r[4], y[4];
#pragma unroll
        for (int p = 0; p < 4; ++p) {
            ln1(xx[p], w, b);
            r[p] = fmaxf(xx[p], 0.0f);
            y[p] = lb[L * 64 + lane];
        }
        const float* W = lw + L * 4096;
#pragma unroll 8
        for (int i = 0; i < 64; ++i) {
            float wi = W[i * 64 + lane];
#pragma unroll
            for (int p = 0; p < 4; ++p)
                y[p] = fmaf(__shfl(r[p], i), wi, y[p]);
        }
#pragma unroll
        for (int p = 0; p < 4; ++p) xx[p] = y[p];
    }
    {
        float w = oln_w[lane], b = oln_b[lane];
#pragma unroll
        for (int p = 0; p < 4; ++p) {
            ln1(xx[p], w, b);
            xx[p] = fmaxf(xx[p], 0.0f);      // relu -> input of out matmul
        }
    }

    float acc[4][8];
#pragma unroll
    for (int k = 0; k < 8; ++k) {
        float ob = out_b[k * 64 + lane];
#pragma unroll
        for (int p = 0; p < 4; ++p) acc[p][k] = ob;
    }
#pragma unroll 4
    for (int i = 0; i < 64; ++i) {
        float a0 = __shfl(xx[0], i), a1 = __shfl(xx[1], i);
        float a2 = __shfl(xx[2], i), a3 = __shfl(xx[3], i);
        const float* Wr = out_w + i * 512;
#pragma unroll
        for (int k = 0; k < 8; ++k) {
            float wv = Wr[k * 64 + lane];
            acc[0][k] = fmaf(a0, wv, acc[0][k]);
            acc[1][k] = fmaf(a1, wv, acc[1][k]);
            acc[2][k] = fmaf(a2, wv, acc[2][k]);
            acc[3][k] = fmaf(a3, wv, acc[3][k]);
        }
    }
    const float LOGG = -0.0010005003335835335f; // ln(0.999)
    float dy[4];
#pragma unroll
    for (int p = 0; p < 4; ++p) dy[p] = __expf(mm[p] * LOGG);  // gamma^m
#pragma unroll
    for (int k = 0; k < 8; ++k) {
        int c = k * 64 + lane;
        float4 o;
        float v;
        v = acc[0][k] * dy[0]; o.x = v / (1.0f + __expf(-v));
        v = acc[1][k] * dy[1]; o.y = v / (1.0f + __expf(-v));
        v = acc[2][k] * dy[2]; o.z = v / (1.0f + __expf(-v));
        v = acc[3][k] * dy[3]; o.w = v / (1.0f + __expf(-v));
        *(float4*)(aT + (size_t)c * 4096 + mbase) = o;   // 16B-aligned (mbase%4==0)
    }
}

// ---------------------------------------------------------------- out transpose
// dst[c][r] = src[r][c], per slab of R*C. grid = (C/64, R/64, slabs), 256 thr.
__global__ __launch_bounds__(256) void k_transpose(const float* __restrict__ src,
                                                   float* __restrict__ dst,
                                                   int R, int C) {
    __shared__ float tile[64][65];
    size_t slab = (size_t)blockIdx.z * (size_t)R * (size_t)C;
    int c0 = blockIdx.x * 64, r0 = blockIdx.y * 64;
    int t = threadIdx.x;
    int tc = t & 63, t4 = t >> 6;
    const float* s = src + slab + (size_t)r0 * C + c0;
#pragma unroll
    for (int k = 0; k < 16; ++k) {
        int rr = t4 + k * 4;
        tile[rr][tc] = s[(size_t)rr * C + tc];
    }
    __syncthreads();
    float* d = dst + slab + (size_t)c0 * R + r0;
#pragma unroll
    for (int k = 0; k < 16; ++k) {
        int cc = t4 + k * 4;
        d[(size_t)cc * R + tc] = tile[tc][cc];
    }
}

// ---------------------------------------------------------------- register FFT
// 4096 = 16^3, 256 threads x 16 cplx in VGPRs, 3 radix-16 stages, 2 LDS
// exchanges on an interleaved float2 buffer (half the LDS instrs of SoA).
static __device__ __forceinline__ void cmulrw(float& r, float& i, float wr, float wi) {
    float t = r * wr - i * wi;
    i = r * wi + i * wr;
    r = t;
}

template<bool INV>
static __device__ __forceinline__ void dft4(float& ar, float& ai, float& br, float& bi,
                                            float& cr, float& ci, float& dr, float& di) {
    float t0r = ar + cr, t0i = ai + ci, t1r = ar - cr, t1i = ai - ci;
    float t2r = br + dr, t2i = bi + di, t3r = br - dr, t3i = bi - di;
    float u3r = INV ? -t3i : t3i;
    float u3i = INV ?  t3r : -t3r;
    ar = t0r + t2r; ai = t0i + t2i;
    br = t1r + u3r; bi = t1i + u3i;
    cr = t0r - t2r; ci = t0i - t2i;
    dr = t1r - u3r; di = t1i - u3i;
}

// In-place DFT-16 (natural in, natural out), compile-time twiddles.
template<bool INV>
static __device__ __forceinline__ void radix16(float (&vr)[16], float (&vi)[16]) {
    const float C1 = 0.92387953251128674f;  // cos(pi/8)
    const float S1 = 0.38268343236508978f;  // sin(pi/8)
    const float R2 = 0.70710678118654752f;
    const float SG = INV ? 1.0f : -1.0f;
#pragma unroll
    for (int na = 0; na < 4; ++na)
        dft4<INV>(vr[na], vi[na], vr[na + 4], vi[na + 4],
                  vr[na + 8], vi[na + 8], vr[na + 12], vi[na + 12]);
    cmulrw(vr[5],  vi[5],   C1, SG * S1);   // m=1
    cmulrw(vr[9],  vi[9],   R2, SG * R2);   // m=2
    cmulrw(vr[13], vi[13],  S1, SG * C1);   // m=3
    cmulrw(vr[6],  vi[6],   R2, SG * R2);   // m=2
    {   // m=4: fwd *(0,-1); inv *(0,+1)
        float tmp = vr[10];
        if (INV) { vr[10] = -vi[10]; vi[10] =  tmp; }
        else     { vr[10] =  vi[10]; vi[10] = -tmp; }
    }
    cmulrw(vr[14], vi[14], -R2, SG * R2);   // m=6
    cmulrw(vr[7],  vi[7],   S1, SG * C1);   // m=3
    cmulrw(vr[11], vi[11], -R2, SG * R2);   // m=6
    cmulrw(vr[15], vi[15], -C1, -SG * S1);  // m=9
    float yr[16], yi[16];
#pragma unroll
    for (int kb = 0; kb < 4; ++kb) {
        float ar = vr[4*kb+0], ai = vi[4*kb+0], br = vr[4*kb+1], bi = vi[4*kb+1];
        float cr = vr[4*kb+2], ci = vi[4*kb+2], dr = vr[4*kb+3], di = vi[4*kb+3];
        dft4<INV>(ar, ai, br, bi, cr, ci, dr, di);
        yr[kb]      = ar; yi[kb]      = ai;
        yr[kb + 4]  = br; yi[kb + 4]  = bi;
        yr[kb + 8]  = cr; yi[kb + 8]  = ci;
        yr[kb + 12] = dr; yi[kb + 12] = di;
    }
#pragma unroll
    for (int k = 0; k < 16; ++k) { vr[k] = yr[k]; vi[k] = yi[k]; }
}

// Full 4096-pt FFT. In: thread t holds x[t + 256*n3] in vr/vi[n3].
// Out: thread t holds X[t + 256*k1] in vr/vi[k1]. Twiddles on the fly.
template<bool INV>
static __device__ __forceinline__ void fft4096_reg(float (&vr)[16], float (&vi)[16],
                                                   float2* __restrict__ lds, int t)
{
    radix16<INV>(vr, vi);                       // over n3 -> k3
    __syncthreads();
#pragma unroll
    for (int k3 = 0; k3 < 16; ++k3)
        lds[pf(t + (k3 << 8))] = make_float2(vr[k3], vi[k3]);
    __syncthreads();
    {   // thread t = n1 + 16*k3 ; read over n2, twiddle W256^(n2*k3)
        int n1 = t & 15, k3 = t >> 4;
        float ang = (float)k3 * (1.0f / 128.0f);
        float wr = cospif(ang);
        float wi = INV ? sinpif(ang) : -sinpif(ang);
        float cr = 1.0f, ci = 0.0f;
#pragma unroll
        for (int n2 = 0; n2 < 16; ++n2) {
            float2 v = lds[pf(n1 + (n2 << 4) + (k3 << 8))];
            vr[n2] = v.x * cr - v.y * ci;
            vi[n2] = v.x * ci + v.y * cr;
            float ncr = cr * wr - ci * wi;
            ci = cr * wi + ci * wr; cr = ncr;
        }
    }
    radix16<INV>(vr, vi);                       // over n2 -> k2
    __syncthreads();
#pragma unroll
    for (int k2 = 0; k2 < 16; ++k2)
        lds[pf(t + (k2 << 8))] = make_float2(vr[k2], vi[k2]);
    __syncthreads();
    {   // thread t = k3 + 16*k2 ; read 16 consecutive, twiddle W4096^(n1*t)
        float ang = (float)t * (1.0f / 2048.0f);
        float wr = cospif(ang);
        float wi = INV ? sinpif(ang) : -sinpif(ang);
        float cr = 1.0f, ci = 0.0f;
#pragma unroll
        for (int n1 = 0; n1 < 16; ++n1) {
            float2 v = lds[pf((t << 4) + n1)];  // contiguous after pad
            vr[n1] = v.x * cr - v.y * ci;
            vi[n1] = v.x * ci + v.y * cr;
            float ncr = cr * wr - ci * wi;
            ci = cr * wi + ci * wr; cr = ncr;
        }
    }
    radix16<INV>(vr, vi);                       // over n1 -> k1
}

// ---------------------------------------------------------------- forward FFT (a-side)
__global__ __launch_bounds__(256, 4) void k_fft_fwd(const float2* __restrict__ src,
                                                    float2* __restrict__ dst) {
    __shared__ float2 lds[LP2];
    const int t = threadIdx.x;
    const float2* s = src + (size_t)blockIdx.x * 2048;
    float vr[16], vi[16];
#pragma unroll
    for (int n3 = 0; n3 < 8; ++n3) {
        float2 v = s[t + (n3 << 8)];
        vr[n3] = v.x; vi[n3] = v.y;
    }
#pragma unroll
    for (int n3 = 8; n3 < 16; ++n3) { vr[n3] = 0.0f; vi[n3] = 0.0f; }
    fft4096_reg<false>(vr, vi, lds, t);
    float2* d = dst + (size_t)blockIdx.x * 4096;
#pragma unroll
    for (int k1 = 0; k1 < 16; ++k1)
        d[t + (k1 << 8)] = make_float2(vr[k1], vi[k1]);
}

// ---------------------------------------------------------------- fused FFT(x)+conv+iFFT
__global__ __launch_bounds__(256, 4) void k_fft_conv_inv(const float2* __restrict__ xrow,
                                                         const float2* __restrict__ Za,
                                                         float* __restrict__ yT) {
    __shared__ float2 lds[LP2];
    const int t = threadIdx.x;
    const int bc = blockIdx.x;          // 0..2047
    const int ca = bc & 511;            // h*64 + d
    const float2* s = xrow + (size_t)bc * 2048;
    float vr[16], vi[16];
#pragma unroll
    for (int n3 = 0; n3 < 8; ++n3) {
        float2 v = s[t + (n3 << 8)];
        vr[n3] = v.x; vi[n3] = v.y;
    }
#pragma unroll
    for (int n3 = 8; n3 < 16; ++n3) { vr[n3] = 0.0f; vi[n3] = 0.0f; }
    fft4096_reg<false>(vr, vi, lds, t);            // X[t + 256*k1] in regs

    __syncthreads();                                // last exchange readers done
#pragma unroll
    for (int k1 = 0; k1 < 16; ++k1)                 // stage spectrum to LDS
        lds[pf(t + (k1 << 8))] = make_float2(vr[k1], vi[k1]);
    __syncthreads();

    const float2* za = Za + (size_t)ca * 4096;
    // Each (f, 4096-f) pair is owned by exactly one thread -> in-place safe.
    for (int f = t; f <= 2048; f += 256) {
        const int fm = (4096 - f) & 4095;
        float2 Xf = lds[pf(f)], Xm = lds[pf(fm)];
        float2 Af = za[f], Am = za[fm];
        // even/odd sub-spectra: E = (Z[f]+conj(Z[-f]))/2, O = -i(Z[f]-conj(Z[-f]))/2
        float Exr = 0.5f * (Xf.x + Xm.x), Exi = 0.5f * (Xf.y - Xm.y);
        float Oxr = 0.5f * (Xf.y + Xm.y), Oxi = 0.5f * (Xm.x - Xf.x);
        float Ear = 0.5f * (Af.x + Am.x), Eai = 0.5f * (Af.y - Am.y);
        float Oar = 0.5f * (Af.y + Am.y), Oai = 0.5f * (Am.x - Af.x);
        // t = e^{-i*pi*f/4096}
        float fr = (float)f * (1.0f / 4096.0f);
        float cp = cospif(fr), sp = sinpif(fr);
        float tOxr = cp * Oxr + sp * Oxi, tOxi = cp * Oxi - sp * Oxr;
        float tOar = cp * Oar + sp * Oai, tOai = cp * Oai - sp * Oar;
        float Xpr = Exr + tOxr, Xpi = Exi + tOxi;   // X8192[f]
        float Xqr = Exr - tOxr, Xqi = Exi - tOxi;   // X8192[f+4096]
        float Apr = Ear + tOar, Api = Eai + tOai;
        float Aqr = Ear - tOar, Aqi = Eai - tOai;
        float Pr = Xpr * Apr - Xpi * Api, Pi = Xpr * Api + Xpi * Apr;
        float Qr = Xqr * Aqr - Xqi * Aqi, Qi = Xqr * Aqi + Xqi * Aqr;
        // Ye = (P+Q)/2 ; Yo = conj(t)*(P-Q)/2 ; W = Ye + i*Yo
        float Sr = 0.5f * (Pr + Qr), Si = 0.5f * (Pi + Qi);
        float Dr = 0.5f * (Pr - Qr), Di = 0.5f * (Pi - Qi);
        float Cr = cp * Dr - sp * Di, Ci = cp * Di + sp * Dr;
        lds[pf(f)]  = make_float2(Sr - Ci, Si + Cr);
        lds[pf(fm)] = make_float2(Sr + Ci, Cr - Si);  // W[-f] = conj(Ye - i*Yo)
    }
    __syncthreads();
#pragma unroll
    for (int n3 = 0; n3 < 16; ++n3) {               // load W for inverse FFT
        float2 v = lds[pf(t + (n3 << 8))];
        vr[n3] = v.x; vi[n3] = v.y;
    }
    fft4096_reg<true>(vr, vi, lds, t);              // y packed in regs

    const float sc = 1.0f / 4096.0f;
    float2* dst = (float2*)yT + (size_t)bc * 2048;
#pragma unroll
    for (int k1 = 0; k1 < 8; ++k1) {                // first 2048 cplx = 4096 reals
        int idx = t + (k1 << 8);
        dst[idx] = make_float2(vr[k1] * sc, vi[k1] * sc);
    }
}

// ---------------------------------------------------------------- launch
extern "C" void kernel_launch(void* const* d_in, const int* in_sizes, int n_in,
                              void* d_out, int out_size, void* d_ws, size_t ws_size,
                              hipStream_t stream) {
    const float* x     = (const float*)d_in[0];
    const float* pp_w  = (const float*)d_in[1];
    const float* pp_b  = (const float*)d_in[2];
    const float* ln_w  = (const float*)d_in[3];
    const float* ln_b  = (const float*)d_in[4];
    const float* lw    = (const float*)d_in[5];
    const float* lb    = (const float*)d_in[6];
    const float* oln_w = (const float*)d_in[7];
    const float* oln_b = (const float*)d_in[8];
    const float* out_w = (const float*)d_in[9];
    const float* out_b = (const float*)d_in[10];
    float* out = (float*)d_out;
    char* ws = (char*)d_ws;

    // ws layout (bytes), total ~58.7 MB:
    //   xT @ 0         : 2048x4096 f32  (33.55 MB)  x channel-major; aliased by yT
    //   aT @ 33554432  : 512x4096  f32  ( 8.39 MB)  silu(decay*rpe), channel-major
    //   Za @ 41943040  : 512x4096  cplx (16.78 MB)  packed spectra of a
    float*  xT = (float*)(ws);
    float*  aT = (float*)(ws + 33554432u);
    float2* Za = (float2*)(ws + 41943040u);
    float*  yT = xT;   // xT dead after the fused kernel consumes it (per-block RAW-safe)

    // 1: x-transpose (blocks 0..2047) + RPE->aT (blocks 2048..2303)
    k_pre<<<2304, 256, 0, stream>>>(x, pp_w, pp_b, ln_w, ln_b, lw, lb,
                                    oln_w, oln_b, out_w, out_b, xT, aT);
    // 2: forward FFT of a-channels
    k_fft_fwd<<<CHA, 256, 0, stream>>>((const float2*)aT, Za);
    // 3: fused FFT(x) * Za -> iFFT -> yT
    k_fft_conv_inv<<<CHX, 256, 0, stream>>>((const float2*)xT, Za, yT);
    // 4: yT [32][64 d][4096 n] -> out [32][4096 n][64 d]
    k_transpose<<<dim3(64, 1, 32), 256, 0, stream>>>(yT, out, 64, 4096);
}

// Round 9
// 179.331 us; speedup vs baseline: 1.0723x; 1.0723x over previous
//
#include <hip/hip_runtime.h>
#include <math.h>

// Problem constants
#define NSEQ 4096      // N
#define MFT  4096      // complex FFT length (even/odd pack of 2N=8192 real)
#define CHX  2048      // B*H*D channels of x
#define CHA  512       // H*D channels of a

// float2-LDS padding: i + (i>>5); max padded index 4095+127=4222 -> 4224 f2.
// Keeps every exchange read/write phase <=2-way bank aliasing (free, m136),
// and exchange-2's 16 consecutive reads stay contiguous after padding.
#define LP2 4224
static __device__ __forceinline__ int pf(int i) { return i + (i >> 5); }

// ---------------------------------------------------------------- wave reduce
static __device__ __forceinline__ float wsum64(float v) {
    v += __shfl_xor(v, 1);
    v += __shfl_xor(v, 2);
    v += __shfl_xor(v, 4);
    v += __shfl_xor(v, 8);
    v += __shfl_xor(v, 16);
    v += __shfl_xor(v, 32);
    return v;
}

static __device__ __forceinline__ void ln_pair(float& x0, float& x1, float w, float b) {
    float mu0 = wsum64(x0) * (1.0f / 64.0f);
    float mu1 = wsum64(x1) * (1.0f / 64.0f);
    float d0 = x0 - mu0, d1 = x1 - mu1;
    float v0 = wsum64(d0 * d0) * (1.0f / 64.0f);
    float v1 = wsum64(d1 * d1) * (1.0f / 64.0f);
    x0 = d0 * rsqrtf(v0 + 1e-5f) * w + b;
    x1 = d1 * rsqrtf(v1 + 1e-5f) * w + b;
}

// ---------------------------------------------------------------- k_pre
// blocks [0,512):    RPE MLP, 2 positions/wave, writes aT[c][m] directly.
// blocks [512,2560): transpose x [32 slabs][4096 n][64 d] -> xT [32][64][4096]
// RPE FIRST + SPLIT: all 512 RPE blocks resident from t=0 (8 blocks/CU cap,
// first ~2048 blocks resident immediately) so shfl/LN latency chains hide
// under the concurrent BW-bound transpose blocks (H1), AND each wave's
// dependent-FMA chain is halved vs the 4-pos version (H2). R5 evidence:
// RPE as a 256-block tail = 47us at 15% occupancy.
//   aT[c][m] = silu(gamma^m * rpe(m)[c]),  c = h*64+d.
// (The reference's trailing zero-row a[4096] only multiplies zero-padded x
//  for all kept outputs n<4096 -> dropped.)
__global__ __launch_bounds__(256) void k_pre(
    const float* __restrict__ x,
    const float* __restrict__ pp_w, const float* __restrict__ pp_b,
    const float* __restrict__ ln_w, const float* __restrict__ ln_b,
    const float* __restrict__ lw,   const float* __restrict__ lb,
    const float* __restrict__ oln_w,const float* __restrict__ oln_b,
    const float* __restrict__ out_w,const float* __restrict__ out_b,
    float* __restrict__ xT, float* __restrict__ aT)
{
    __shared__ float tile[64][65];
    const int t = threadIdx.x;

    if (blockIdx.x >= 512) {                 // ---- x transpose (R=4096, C=64)
        const int bid = blockIdx.x - 512;    // 0..2047
        const int slab = bid >> 6;           // 0..31
        const int r0 = (bid & 63) * 64;
        const size_t base = (size_t)slab * 262144u;
        const int tc = t & 63, t4 = t >> 6;
        const float* s = x + base + (size_t)r0 * 64;
#pragma unroll
        for (int k = 0; k < 16; ++k) {
            int rr = t4 + k * 4;
            tile[rr][tc] = s[rr * 64 + tc];
        }
        __syncthreads();
        float* d = xT + base + r0;
#pragma unroll
        for (int k = 0; k < 16; ++k) {
            int cc = t4 + k * 4;
            d[(size_t)cc * 4096 + tc] = tile[tc][cc];
        }
        return;
    }

    // ---------------- RPE path (blocks 0..511), 2 positions per wave
    const int wave = t >> 6;
    const int lane = t & 63;
    const int mbase = ((int)blockIdx.x * 4 + wave) * 2;  // 0..4094, even
    const float m0 = (float)mbase, m1 = (float)(mbase + 1);

    float x0 = fmaf(m0, pp_w[lane], pp_b[lane]);
    float x1 = fmaf(m1, pp_w[lane], pp_b[lane]);

    for (int L = 0; L < 3; ++L) {
        ln_pair(x0, x1, ln_w[L * 64 + lane], ln_b[L * 64 + lane]);
        float r0 = fmaxf(x0, 0.0f), r1 = fmaxf(x1, 0.0f);
        float y0 = lb[L * 64 + lane], y1 = y0;
        const float* W = lw + L * 4096;
#pragma unroll 8
        for (int i = 0; i < 64; ++i) {
            float wi = W[i * 64 + lane];
            y0 = fmaf(__shfl(r0, i), wi, y0);
            y1 = fmaf(__shfl(r1, i), wi, y1);
        }
        x0 = y0; x1 = y1;
    }
    ln_pair(x0, x1, oln_w[lane], oln_b[lane]);
    float r0 = fmaxf(x0, 0.0f), r1 = fmaxf(x1, 0.0f);

    float acc0[8], acc1[8];
#pragma unroll
    for (int k = 0; k < 8; ++k) {
        float ob = out_b[k * 64 + lane];
        acc0[k] = ob; acc1[k] = ob;
    }
#pragma unroll 4
    for (int i = 0; i < 64; ++i) {
        float a0 = __shfl(r0, i);
        float a1 = __shfl(r1, i);
        const float* Wr = out_w + i * 512;
#pragma unroll
        for (int k = 0; k < 8; ++k) {
            float wv = Wr[k * 64 + lane];
            acc0[k] = fmaf(a0, wv, acc0[k]);
            acc1[k] = fmaf(a1, wv, acc1[k]);
        }
    }
    const float LOGG = -0.0010005003335835335f; // ln(0.999)
    float d0 = __expf(m0 * LOGG);               // gamma^m (m0==0 -> 1)
    float d1 = __expf(m1 * LOGG);
#pragma unroll
    for (int k = 0; k < 8; ++k) {
        int c = k * 64 + lane;
        float2 o;
        float v;
        v = acc0[k] * d0; o.x = v / (1.0f + __expf(-v));
        v = acc1[k] * d1; o.y = v / (1.0f + __expf(-v));
        *(float2*)(aT + (size_t)c * 4096 + mbase) = o;   // 8B-aligned (mbase even)
    }
}

// ---------------------------------------------------------------- out transpose
// dst[c][r] = src[r][c], per slab of R*C. grid = (C/64, R/64, slabs), 256 thr.
__global__ __launch_bounds__(256) void k_transpose(const float* __restrict__ src,
                                                   float* __restrict__ dst,
                                                   int R, int C) {
    __shared__ float tile[64][65];
    size_t slab = (size_t)blockIdx.z * (size_t)R * (size_t)C;
    int c0 = blockIdx.x * 64, r0 = blockIdx.y * 64;
    int t = threadIdx.x;
    int tc = t & 63, t4 = t >> 6;
    const float* s = src + slab + (size_t)r0 * C + c0;
#pragma unroll
    for (int k = 0; k < 16; ++k) {
        int rr = t4 + k * 4;
        tile[rr][tc] = s[(size_t)rr * C + tc];
    }
    __syncthreads();
    float* d = dst + slab + (size_t)c0 * R + r0;
#pragma unroll
    for (int k = 0; k < 16; ++k) {
        int cc = t4 + k * 4;
        d[(size_t)cc * R + tc] = tile[tc][cc];
    }
}

// ---------------------------------------------------------------- register FFT
// 4096 = 16^3, 256 threads x 16 cplx in VGPRs, 3 radix-16 stages, 2 LDS
// exchanges on an interleaved float2 buffer (half the LDS instrs of SoA).
static __device__ __forceinline__ void cmulrw(float& r, float& i, float wr, float wi) {
    float t = r * wr - i * wi;
    i = r * wi + i * wr;
    r = t;
}

template<bool INV>
static __device__ __forceinline__ void dft4(float& ar, float& ai, float& br, float& bi,
                                            float& cr, float& ci, float& dr, float& di) {
    float t0r = ar + cr, t0i = ai + ci, t1r = ar - cr, t1i = ai - ci;
    float t2r = br + dr, t2i = bi + di, t3r = br - dr, t3i = bi - di;
    float u3r = INV ? -t3i : t3i;
    float u3i = INV ?  t3r : -t3r;
    ar = t0r + t2r; ai = t0i + t2i;
    br = t1r + u3r; bi = t1i + u3i;
    cr = t0r - t2r; ci = t0i - t2i;
    dr = t1r - u3r; di = t1i - u3i;
}

// In-place DFT-16 (natural in, natural out), compile-time twiddles.
template<bool INV>
static __device__ __forceinline__ void radix16(float (&vr)[16], float (&vi)[16]) {
    const float C1 = 0.92387953251128674f;  // cos(pi/8)
    const float S1 = 0.38268343236508978f;  // sin(pi/8)
    const float R2 = 0.70710678118654752f;
    const float SG = INV ? 1.0f : -1.0f;
#pragma unroll
    for (int na = 0; na < 4; ++na)
        dft4<INV>(vr[na], vi[na], vr[na + 4], vi[na + 4],
                  vr[na + 8], vi[na + 8], vr[na + 12], vi[na + 12]);
    cmulrw(vr[5],  vi[5],   C1, SG * S1);   // m=1
    cmulrw(vr[9],  vi[9],   R2, SG * R2);   // m=2
    cmulrw(vr[13], vi[13],  S1, SG * C1);   // m=3
    cmulrw(vr[6],  vi[6],   R2, SG * R2);   // m=2
    {   // m=4: fwd *(0,-1); inv *(0,+1)
        float tmp = vr[10];
        if (INV) { vr[10] = -vi[10]; vi[10] =  tmp; }
        else     { vr[10] =  vi[10]; vi[10] = -tmp; }
    }
    cmulrw(vr[14], vi[14], -R2, SG * R2);   // m=6
    cmulrw(vr[7],  vi[7],   S1, SG * C1);   // m=3
    cmulrw(vr[11], vi[11], -R2, SG * R2);   // m=6
    cmulrw(vr[15], vi[15], -C1, -SG * S1);  // m=9
    float yr[16], yi[16];
#pragma unroll
    for (int kb = 0; kb < 4; ++kb) {
        float ar = vr[4*kb+0], ai = vi[4*kb+0], br = vr[4*kb+1], bi = vi[4*kb+1];
        float cr = vr[4*kb+2], ci = vi[4*kb+2], dr = vr[4*kb+3], di = vi[4*kb+3];
        dft4<INV>(ar, ai, br, bi, cr, ci, dr, di);
        yr[kb]      = ar; yi[kb]      = ai;
        yr[kb + 4]  = br; yi[kb + 4]  = bi;
        yr[kb + 8]  = cr; yi[kb + 8]  = ci;
        yr[kb + 12] = dr; yi[kb + 12] = di;
    }
#pragma unroll
    for (int k = 0; k < 16; ++k) { vr[k] = yr[k]; vi[k] = yi[k]; }
}

// Full 4096-pt FFT. In: thread t holds x[t + 256*n3] in vr/vi[n3].
// Out: thread t holds X[t + 256*k1] in vr/vi[k1]. Twiddles on the fly.
template<bool INV>
static __device__ __forceinline__ void fft4096_reg(float (&vr)[16], float (&vi)[16],
                                                   float2* __restrict__ lds, int t)
{
    radix16<INV>(vr, vi);                       // over n3 -> k3
    __syncthreads();
#pragma unroll
    for (int k3 = 0; k3 < 16; ++k3)
        lds[pf(t + (k3 << 8))] = make_float2(vr[k3], vi[k3]);
    __syncthreads();
    {   // thread t = n1 + 16*k3 ; read over n2, twiddle W256^(n2*k3)
        int n1 = t & 15, k3 = t >> 4;
        float ang = (float)k3 * (1.0f / 128.0f);
        float wr = cospif(ang);
        float wi = INV ? sinpif(ang) : -sinpif(ang);
        float cr = 1.0f, ci = 0.0f;
#pragma unroll
        for (int n2 = 0; n2 < 16; ++n2) {
            float2 v = lds[pf(n1 + (n2 << 4) + (k3 << 8))];
            vr[n2] = v.x * cr - v.y * ci;
            vi[n2] = v.x * ci + v.y * cr;
            float ncr = cr * wr - ci * wi;
            ci = cr * wi + ci * wr; cr = ncr;
        }
    }
    radix16<INV>(vr, vi);                       // over n2 -> k2
    __syncthreads();
#pragma unroll
    for (int k2 = 0; k2 < 16; ++k2)
        lds[pf(t + (k2 << 8))] = make_float2(vr[k2], vi[k2]);
    __syncthreads();
    {   // thread t = k3 + 16*k2 ; read 16 consecutive, twiddle W4096^(n1*t)
        float ang = (float)t * (1.0f / 2048.0f);
        float wr = cospif(ang);
        float wi = INV ? sinpif(ang) : -sinpif(ang);
        float cr = 1.0f, ci = 0.0f;
#pragma unroll
        for (int n1 = 0; n1 < 16; ++n1) {
            float2 v = lds[pf((t << 4) + n1)];  // contiguous after pad
            vr[n1] = v.x * cr - v.y * ci;
            vi[n1] = v.x * ci + v.y * cr;
            float ncr = cr * wr - ci * wi;
            ci = cr * wi + ci * wr; cr = ncr;
        }
    }
    radix16<INV>(vr, vi);                       // over n1 -> k1
}

// ---------------------------------------------------------------- forward FFT (a-side)
__global__ __launch_bounds__(256, 4) void k_fft_fwd(const float2* __restrict__ src,
                                                    float2* __restrict__ dst) {
    __shared__ float2 lds[LP2];
    const int t = threadIdx.x;
    const float2* s = src + (size_t)blockIdx.x * 2048;
    float vr[16], vi[16];
#pragma unroll
    for (int n3 = 0; n3 < 8; ++n3) {
        float2 v = s[t + (n3 << 8)];
        vr[n3] = v.x; vi[n3] = v.y;
    }
#pragma unroll
    for (int n3 = 8; n3 < 16; ++n3) { vr[n3] = 0.0f; vi[n3] = 0.0f; }
    fft4096_reg<false>(vr, vi, lds, t);
    float2* d = dst + (size_t)blockIdx.x * 4096;
#pragma unroll
    for (int k1 = 0; k1 < 16; ++k1)
        d[t + (k1 << 8)] = make_float2(vr[k1], vi[k1]);
}

// ---------------------------------------------------------------- fused FFT(x)+conv+iFFT
__global__ __launch_bounds__(256, 4) void k_fft_conv_inv(const float2* __restrict__ xrow,
                                                         const float2* __restrict__ Za,
                                                         float* __restrict__ yT) {
    __shared__ float2 lds[LP2];
    const int t = threadIdx.x;
    const int bc = blockIdx.x;          // 0..2047
    const int ca = bc & 511;            // h*64 + d
    const float2* s = xrow + (size_t)bc * 2048;
    float vr[16], vi[16];
#pragma unroll
    for (int n3 = 0; n3 < 8; ++n3) {
        float2 v = s[t + (n3 << 8)];
        vr[n3] = v.x; vi[n3] = v.y;
    }
#pragma unroll
    for (int n3 = 8; n3 < 16; ++n3) { vr[n3] = 0.0f; vi[n3] = 0.0f; }
    fft4096_reg<false>(vr, vi, lds, t);            // X[t + 256*k1] in regs

    __syncthreads();                                // last exchange readers done
#pragma unroll
    for (int k1 = 0; k1 < 16; ++k1)                 // stage spectrum to LDS
        lds[pf(t + (k1 << 8))] = make_float2(vr[k1], vi[k1]);
    __syncthreads();

    const float2* za = Za + (size_t)ca * 4096;
    // Each (f, 4096-f) pair is owned by exactly one thread -> in-place safe.
    for (int f = t; f <= 2048; f += 256) {
        const int fm = (4096 - f) & 4095;
        float2 Xf = lds[pf(f)], Xm = lds[pf(fm)];
        float2 Af = za[f], Am = za[fm];
        // even/odd sub-spectra: E = (Z[f]+conj(Z[-f]))/2, O = -i(Z[f]-conj(Z[-f]))/2
        float Exr = 0.5f * (Xf.x + Xm.x), Exi = 0.5f * (Xf.y - Xm.y);
        float Oxr = 0.5f * (Xf.y + Xm.y), Oxi = 0.5f * (Xm.x - Xf.x);
        float Ear = 0.5f * (Af.x + Am.x), Eai = 0.5f * (Af.y - Am.y);
        float Oar = 0.5f * (Af.y + Am.y), Oai = 0.5f * (Am.x - Af.x);
        // t = e^{-i*pi*f/4096}
        float fr = (float)f * (1.0f / 4096.0f);
        float cp = cospif(fr), sp = sinpif(fr);
        float tOxr = cp * Oxr + sp * Oxi, tOxi = cp * Oxi - sp * Oxr;
        float tOar = cp * Oar + sp * Oai, tOai = cp * Oai - sp * Oar;
        float Xpr = Exr + tOxr, Xpi = Exi + tOxi;   // X8192[f]
        float Xqr = Exr - tOxr, Xqi = Exi - tOxi;   // X8192[f+4096]
        float Apr = Ear + tOar, Api = Eai + tOai;
        float Aqr = Ear - tOar, Aqi = Eai - tOai;
        float Pr = Xpr * Apr - Xpi * Api, Pi = Xpr * Api + Xpi * Apr;
        float Qr = Xqr * Aqr - Xqi * Aqi, Qi = Xqr * Aqi + Xqi * Aqr;
        // Ye = (P+Q)/2 ; Yo = conj(t)*(P-Q)/2 ; W = Ye + i*Yo
        float Sr = 0.5f * (Pr + Qr), Si = 0.5f * (Pi + Qi);
        float Dr = 0.5f * (Pr - Qr), Di = 0.5f * (Pi - Qi);
        float Cr = cp * Dr - sp * Di, Ci = cp * Di + sp * Dr;
        lds[pf(f)]  = make_float2(Sr - Ci, Si + Cr);
        lds[pf(fm)] = make_float2(Sr + Ci, Cr - Si);  // W[-f] = conj(Ye - i*Yo)
    }
    __syncthreads();
#pragma unroll
    for (int n3 = 0; n3 < 16; ++n3) {               // load W for inverse FFT
        float2 v = lds[pf(t + (n3 << 8))];
        vr[n3] = v.x; vi[n3] = v.y;
    }
    fft4096_reg<true>(vr, vi, lds, t);              // y packed in regs

    const float sc = 1.0f / 4096.0f;
    float2* dst = (float2*)yT + (size_t)bc * 2048;
#pragma unroll
    for (int k1 = 0; k1 < 8; ++k1) {                // first 2048 cplx = 4096 reals
        int idx = t + (k1 << 8);
        dst[idx] = make_float2(vr[k1] * sc, vi[k1] * sc);
    }
}

// ---------------------------------------------------------------- launch
extern "C" void kernel_launch(void* const* d_in, const int* in_sizes, int n_in,
                              void* d_out, int out_size, void* d_ws, size_t ws_size,
                              hipStream_t stream) {
    const float* x     = (const float*)d_in[0];
    const float* pp_w  = (const float*)d_in[1];
    const float* pp_b  = (const float*)d_in[2];
    const float* ln_w  = (const float*)d_in[3];
    const float* ln_b  = (const float*)d_in[4];
    const float* lw    = (const float*)d_in[5];
    const float* lb    = (const float*)d_in[6];
    const float* oln_w = (const float*)d_in[7];
    const float* oln_b = (const float*)d_in[8];
    const float* out_w = (const float*)d_in[9];
    const float* out_b = (const float*)d_in[10];
    float* out = (float*)d_out;
    char* ws = (char*)d_ws;

    // ws layout (bytes), total ~58.7 MB:
    //   xT @ 0         : 2048x4096 f32  (33.55 MB)  x channel-major; aliased by yT
    //   aT @ 33554432  : 512x4096  f32  ( 8.39 MB)  silu(decay*rpe), channel-major
    //   Za @ 41943040  : 512x4096  cplx (16.78 MB)  packed spectra of a
    float*  xT = (float*)(ws);
    float*  aT = (float*)(ws + 33554432u);
    float2* Za = (float2*)(ws + 41943040u);
    float*  yT = xT;   // xT dead after the fused kernel consumes it (per-block RAW-safe)

    // 1: RPE->aT (blocks 0..511) + x-transpose (blocks 512..2559)
    k_pre<<<2560, 256, 0, stream>>>(x, pp_w, pp_b, ln_w, ln_b, lw, lb,
                                    oln_w, oln_b, out_w, out_b, xT, aT);
    // 2: forward FFT of a-channels
    k_fft_fwd<<<CHA, 256, 0, stream>>>((const float2*)aT, Za);
    // 3: fused FFT(x) * Za -> iFFT -> yT
    k_fft_conv_inv<<<CHX, 256, 0, stream>>>((const float2*)xT, Za, yT);
    // 4: yT [32][64 d][4096 n] -> out [32][4096 n][64 d]
    k_transpose<<<dim3(64, 1, 32), 256, 0, stream>>>(yT, out, 64, 4096);
}